// Round 1
// baseline (1810.170 us; speedup 1.0000x reference)
//
#include <hip/hip_runtime.h>
#include <cfloat>

#define N_NODES 4096
#define C1_DIM  1001
#define D_DIM   4096
#define HMLP    1024
#define KCAT    (D_DIM + C1_DIM + 4)   // 5101
#define TOPK    32

// ---------------------------------------------------------------------------
// Big GEMM: 128x128 tile, BK=8, 256 threads, 8x8 per thread. fp32.
// C = A(MxK) * B(KxN) + bias[, relu]. Requires M%128==0, N%128==0, K%8==0.
// ---------------------------------------------------------------------------
template<bool RELU>
__global__ __launch_bounds__(256) void gemm_big(
    const float* __restrict__ A, const float* __restrict__ B,
    const float* __restrict__ bias, float* __restrict__ C,
    int M, int Ncols, int K) {
  __shared__ float As[8][128];
  __shared__ float Bs[8][132];
  const int tid = threadIdx.x;
  const int row0 = blockIdx.y * 128, col0 = blockIdx.x * 128;
  const int tx = tid & 15, ty = tid >> 4;
  const int arow = tid >> 1, acol = (tid & 1) * 4;
  const int brow = tid >> 5, bcol = (tid & 31) * 4;

  float acc[8][8];
#pragma unroll
  for (int i = 0; i < 8; ++i)
#pragma unroll
    for (int j = 0; j < 8; ++j) acc[i][j] = 0.f;

  for (int k0 = 0; k0 < K; k0 += 8) {
    const float4 a4 = *(const float4*)(A + (size_t)(row0 + arow) * K + k0 + acol);
    const float4 b4 = *(const float4*)(B + (size_t)(k0 + brow) * Ncols + col0 + bcol);
    __syncthreads();
    As[acol + 0][arow] = a4.x; As[acol + 1][arow] = a4.y;
    As[acol + 2][arow] = a4.z; As[acol + 3][arow] = a4.w;
    *(float4*)&Bs[brow][bcol] = b4;
    __syncthreads();
#pragma unroll
    for (int k = 0; k < 8; ++k) {
      float av[8], bw[8];
      *(float4*)&av[0] = *(const float4*)&As[k][ty * 8];
      *(float4*)&av[4] = *(const float4*)&As[k][ty * 8 + 4];
      *(float4*)&bw[0] = *(const float4*)&Bs[k][tx * 4];
      *(float4*)&bw[4] = *(const float4*)&Bs[k][64 + tx * 4];
#pragma unroll
      for (int i = 0; i < 8; ++i)
#pragma unroll
        for (int j = 0; j < 8; ++j) acc[i][j] += av[i] * bw[j];
    }
  }

  float4 blo = *(const float4*)(bias + col0 + tx * 4);
  float4 bhi = *(const float4*)(bias + col0 + 64 + tx * 4);
#pragma unroll
  for (int i = 0; i < 8; ++i) {
    const int r = row0 + ty * 8 + i;
    float* crow = C + (size_t)r * Ncols + col0;
    float4 lo, hi;
    lo.x = acc[i][0] + blo.x; lo.y = acc[i][1] + blo.y;
    lo.z = acc[i][2] + blo.z; lo.w = acc[i][3] + blo.w;
    hi.x = acc[i][4] + bhi.x; hi.y = acc[i][5] + bhi.y;
    hi.z = acc[i][6] + bhi.z; hi.w = acc[i][7] + bhi.w;
    if (RELU) {
      lo.x = fmaxf(lo.x, 0.f); lo.y = fmaxf(lo.y, 0.f);
      lo.z = fmaxf(lo.z, 0.f); lo.w = fmaxf(lo.w, 0.f);
      hi.x = fmaxf(hi.x, 0.f); hi.y = fmaxf(hi.y, 0.f);
      hi.z = fmaxf(hi.z, 0.f); hi.w = fmaxf(hi.w, 0.f);
    }
    *(float4*)(crow + tx * 4) = lo;
    *(float4*)(crow + 64 + tx * 4) = hi;
  }
}

// ---------------------------------------------------------------------------
// GEMM1: A is the on-the-fly concat [query_emb | probs | bbox], K=5101.
// Same tiling as gemm_big, scalar A loads with range routing, K guard.
// Fused bias + relu. N=1024.
// ---------------------------------------------------------------------------
__global__ __launch_bounds__(256) void gemm1_concat(
    const float* __restrict__ q, const float* __restrict__ probs,
    const float* __restrict__ bbox, const float* __restrict__ B,
    const float* __restrict__ bias, float* __restrict__ C) {
  const int Ncols = HMLP, K = KCAT;
  __shared__ float As[8][128];
  __shared__ float Bs[8][132];
  const int tid = threadIdx.x;
  const int row0 = blockIdx.y * 128, col0 = blockIdx.x * 128;
  const int tx = tid & 15, ty = tid >> 4;
  const int arow = tid >> 1, acol = (tid & 1) * 4;
  const int brow = tid >> 5, bcol = (tid & 31) * 4;
  const int gr = row0 + arow;

  float acc[8][8];
#pragma unroll
  for (int i = 0; i < 8; ++i)
#pragma unroll
    for (int j = 0; j < 8; ++j) acc[i][j] = 0.f;

  for (int k0 = 0; k0 < K; k0 += 8) {
    float a[4];
#pragma unroll
    for (int u = 0; u < 4; ++u) {
      const int k = k0 + acol + u;
      float v = 0.f;
      if (k < D_DIM)                 v = q[(size_t)gr * D_DIM + k];
      else if (k < D_DIM + C1_DIM)   v = probs[(size_t)gr * C1_DIM + (k - D_DIM)];
      else if (k < K)                v = bbox[(size_t)gr * 4 + (k - D_DIM - C1_DIM)];
      a[u] = v;
    }
    float4 b4 = make_float4(0.f, 0.f, 0.f, 0.f);
    const int kb = k0 + brow;
    if (kb < K) b4 = *(const float4*)(B + (size_t)kb * Ncols + col0 + bcol);
    __syncthreads();
    As[acol + 0][arow] = a[0]; As[acol + 1][arow] = a[1];
    As[acol + 2][arow] = a[2]; As[acol + 3][arow] = a[3];
    *(float4*)&Bs[brow][bcol] = b4;
    __syncthreads();
#pragma unroll
    for (int k = 0; k < 8; ++k) {
      float av[8], bw[8];
      *(float4*)&av[0] = *(const float4*)&As[k][ty * 8];
      *(float4*)&av[4] = *(const float4*)&As[k][ty * 8 + 4];
      *(float4*)&bw[0] = *(const float4*)&Bs[k][tx * 4];
      *(float4*)&bw[4] = *(const float4*)&Bs[k][64 + tx * 4];
#pragma unroll
      for (int i = 0; i < 8; ++i)
#pragma unroll
        for (int j = 0; j < 8; ++j) acc[i][j] += av[i] * bw[j];
    }
  }

  float4 blo = *(const float4*)(bias + col0 + tx * 4);
  float4 bhi = *(const float4*)(bias + col0 + 64 + tx * 4);
#pragma unroll
  for (int i = 0; i < 8; ++i) {
    const int r = row0 + ty * 8 + i;
    float* crow = C + (size_t)r * Ncols + col0;
    float4 lo, hi;
    lo.x = fmaxf(acc[i][0] + blo.x, 0.f); lo.y = fmaxf(acc[i][1] + blo.y, 0.f);
    lo.z = fmaxf(acc[i][2] + blo.z, 0.f); lo.w = fmaxf(acc[i][3] + blo.w, 0.f);
    hi.x = fmaxf(acc[i][4] + bhi.x, 0.f); hi.y = fmaxf(acc[i][5] + bhi.y, 0.f);
    hi.z = fmaxf(acc[i][6] + bhi.z, 0.f); hi.w = fmaxf(acc[i][7] + bhi.w, 0.f);
    *(float4*)(crow + tx * 4) = lo;
    *(float4*)(crow + 64 + tx * 4) = hi;
  }
}

// ---------------------------------------------------------------------------
// Small GEMM: 64x64 tile, BK=16, 256 threads, 4x4 per thread.
// Requires M%64==0, N%64==0, K%16==0. No bias (bias fused into agg).
// ---------------------------------------------------------------------------
__global__ __launch_bounds__(256) void gemm_small(
    const float* __restrict__ A, const float* __restrict__ B,
    float* __restrict__ C, int M, int Ncols, int K) {
  __shared__ float As[16][68];
  __shared__ float Bs[16][68];
  const int tid = threadIdx.x;
  const int row0 = blockIdx.y * 64, col0 = blockIdx.x * 64;
  const int tx = tid & 15, ty = tid >> 4;
  const int arow = tid >> 2, acol = (tid & 3) * 4;
  const int brow = tid >> 4, bcol = (tid & 15) * 4;

  float acc[4][4];
#pragma unroll
  for (int i = 0; i < 4; ++i)
#pragma unroll
    for (int j = 0; j < 4; ++j) acc[i][j] = 0.f;

  for (int k0 = 0; k0 < K; k0 += 16) {
    const float4 a4 = *(const float4*)(A + (size_t)(row0 + arow) * K + k0 + acol);
    const float4 b4 = *(const float4*)(B + (size_t)(k0 + brow) * Ncols + col0 + bcol);
    __syncthreads();
    As[acol + 0][arow] = a4.x; As[acol + 1][arow] = a4.y;
    As[acol + 2][arow] = a4.z; As[acol + 3][arow] = a4.w;
    *(float4*)&Bs[brow][bcol] = b4;
    __syncthreads();
#pragma unroll
    for (int k = 0; k < 16; ++k) {
      float av[4], bw[4];
      *(float4*)&av[0] = *(const float4*)&As[k][ty * 4];
      *(float4*)&bw[0] = *(const float4*)&Bs[k][tx * 4];
#pragma unroll
      for (int i = 0; i < 4; ++i)
#pragma unroll
        for (int j = 0; j < 4; ++j) acc[i][j] += av[i] * bw[j];
    }
  }

#pragma unroll
  for (int i = 0; i < 4; ++i) {
    const int r = row0 + ty * 4 + i;
    float4 v;
    v.x = acc[i][0]; v.y = acc[i][1]; v.z = acc[i][2]; v.w = acc[i][3];
    *(float4*)(C + (size_t)r * Ncols + col0 + tx * 4) = v;
  }
}

// ---------------------------------------------------------------------------
// Top-K: one block per row. Row in LDS; 32 iterative argmax passes
// (tie -> lowest index, matching jax.lax.top_k). Also emits dinv.
// Downstream is permutation-invariant over k, so output order is free.
// ---------------------------------------------------------------------------
__global__ __launch_bounds__(256) void topk_kernel(
    const float* __restrict__ adj, float* __restrict__ vals,
    int* __restrict__ idxo, float* __restrict__ dinv) {
  __shared__ float sv[N_NODES];
  __shared__ float rv[256];
  __shared__ int   ri[256];
  const int n = blockIdx.x, tid = threadIdx.x;
  const float4* rowp = (const float4*)(adj + (size_t)n * N_NODES);
  for (int j = tid; j < N_NODES / 4; j += 256)
    *(float4*)&sv[j * 4] = rowp[j];
  __syncthreads();

  float sum = 0.f;
  for (int it = 0; it < TOPK; ++it) {
    float best = -FLT_MAX; int bi = N_NODES;
    for (int j = tid; j < N_NODES; j += 256) {
      const float v = sv[j];
      if (v > best) { best = v; bi = j; }
    }
    rv[tid] = best; ri[tid] = bi;
    __syncthreads();
    for (int s = 128; s > 0; s >>= 1) {
      if (tid < s) {
        const float ov = rv[tid + s]; const int oi = ri[tid + s];
        if (ov > rv[tid] || (ov == rv[tid] && oi < ri[tid])) { rv[tid] = ov; ri[tid] = oi; }
      }
      __syncthreads();
    }
    if (tid == 0) {
      vals[(size_t)n * TOPK + it] = rv[0];
      idxo[(size_t)n * TOPK + it] = ri[0];
      sv[ri[0]] = -FLT_MAX;
      sum += rv[0];
    }
    __syncthreads();
  }
  if (tid == 0)
    dinv[n] = (sum > 0.f) ? rsqrtf(fmaxf(sum, 1e-12f)) : 0.f;
}

// wn[n,k] = vals[n,k] * dinv[n] * dinv[idx[n,k]]
__global__ void wn_kernel(const float* __restrict__ vals, const int* __restrict__ idxo,
                          const float* __restrict__ dinv, float* __restrict__ wn) {
  const int i = blockIdx.x * 256 + threadIdx.x;   // over N*TOPK
  const int n = i >> 5;
  wn[i] = vals[i] * dinv[n] * dinv[idxo[i]];
}

// out[n,f] = bias[f] + sum_k wn[n,k] * Z[idx[n,k], f]   (F == 256 == blockDim)
__global__ __launch_bounds__(256) void agg_kernel(
    const float* __restrict__ Z, const float* __restrict__ wn,
    const int* __restrict__ idxo, const float* __restrict__ bias,
    float* __restrict__ out) {
  const int n = blockIdx.x, f = threadIdx.x;
  float acc = bias[f];
#pragma unroll
  for (int k = 0; k < TOPK; ++k) {
    const float w = wn[n * TOPK + k];
    const int   j = idxo[n * TOPK + k];
    acc += w * Z[(size_t)j * 256 + f];
  }
  out[(size_t)n * 256 + f] = acc;
}

// BatchNorm stats, deterministic two-stage: partial per 16-row slab, then tree.
__global__ __launch_bounds__(256) void bn_partial(
    const float* __restrict__ x, float* __restrict__ partial) {
  const int b = blockIdx.x, c = threadIdx.x;
  float s = 0.f, s2 = 0.f;
  for (int r = b * 16; r < b * 16 + 16; ++r) {
    const float v = x[(size_t)r * 256 + c];
    s += v; s2 += v * v;
  }
  partial[(size_t)b * 512 + c]       = s;
  partial[(size_t)b * 512 + 256 + c] = s2;
}

__global__ __launch_bounds__(256) void bn_reduce(
    const float* __restrict__ partial, float* __restrict__ colstats) {
  const int j = blockIdx.x, t = threadIdx.x;
  __shared__ float red[256];
  red[t] = partial[(size_t)t * 512 + j];
  __syncthreads();
  for (int s = 128; s > 0; s >>= 1) {
    if (t < s) red[t] += red[t + s];
    __syncthreads();
  }
  if (t == 0) colstats[j] = red[0];
}

__global__ __launch_bounds__(256) void bn_apply(
    float* __restrict__ x, const float* __restrict__ colstats,
    const float* __restrict__ gamma, const float* __restrict__ beta) {
  const int i = blockIdx.x * 256 + threadIdx.x;  // over N*256
  const int c = i & 255;
  const float mean = colstats[c] * (1.f / 4096.f);
  float var = colstats[256 + c] * (1.f / 4096.f) - mean * mean;
  var = fmaxf(var, 0.f);
  const float v = (x[i] - mean) * rsqrtf(var + 1e-5f) * gamma[c] + beta[c];
  x[i] = fmaxf(v, 0.f);
}

// ---------------------------------------------------------------------------
extern "C" void kernel_launch(void* const* d_in, const int* in_sizes, int n_in,
                              void* d_out, int out_size, void* d_ws, size_t ws_size,
                              hipStream_t stream) {
  const float* probs   = (const float*)d_in[0];
  const float* bbox    = (const float*)d_in[1];
  const float* query   = (const float*)d_in[2];
  const float* node    = (const float*)d_in[3];
  const float* mlp_w1  = (const float*)d_in[4];
  const float* mlp_b1  = (const float*)d_in[5];
  const float* mlp_w2  = (const float*)d_in[6];
  const float* mlp_b2  = (const float*)d_in[7];
  const float* conv_w1 = (const float*)d_in[8];
  const float* conv_b1 = (const float*)d_in[9];
  const float* conv_w2 = (const float*)d_in[10];
  const float* conv_b2 = (const float*)d_in[11];
  const float* gamma   = (const float*)d_in[12];
  const float* beta    = (const float*)d_in[13];

  float* ws   = (float*)d_ws;
  float* adj  = ws;                                    // N*N          (67.1 MB)
  float* h    = ws + (size_t)N_NODES * N_NODES;        // N*1024       (16.8 MB)
  float* vals = h  + (size_t)N_NODES * HMLP;           // N*32
  int*   idxo = (int*)(vals + (size_t)N_NODES * TOPK); // N*32
  float* wn   = (float*)idxo + (size_t)N_NODES * TOPK; // N*32
  float* dinv = wn + (size_t)N_NODES * TOPK;           // N
  // adj region reused after topk:
  float* Z1       = adj;                               // N*256
  float* out1     = adj + (size_t)N_NODES * 256;       // N*256
  float* Z2       = adj + (size_t)N_NODES * 512;       // N*256
  float* partial  = adj + (size_t)N_NODES * 768;       // 256*512
  float* colstats = partial + 256 * 512;               // 512

  // 1) h = relu([query|probs|bbox] @ W1 + b1)          (4096 x 1024)
  gemm1_concat<<<dim3(HMLP / 128, N_NODES / 128), 256, 0, stream>>>(
      query, probs, bbox, mlp_w1, mlp_b1, h);
  // 2) adj = h @ W2 + b2                               (4096 x 4096)
  gemm_big<false><<<dim3(N_NODES / 128, N_NODES / 128), 256, 0, stream>>>(
      h, mlp_w2, mlp_b2, adj, N_NODES, N_NODES, HMLP);
  // 3) top-32 per row + dinv
  topk_kernel<<<N_NODES, 256, 0, stream>>>(adj, vals, idxo, dinv);
  // 4) wn
  wn_kernel<<<(N_NODES * TOPK) / 256, 256, 0, stream>>>(vals, idxo, dinv, wn);
  // 5) Z1 = node_emb @ conv_w1                         (4096 x 256)
  gemm_small<<<dim3(256 / 64, N_NODES / 64), 256, 0, stream>>>(
      node, conv_w1, Z1, N_NODES, 256, D_DIM);
  // 6) out1 = gather-agg(Z1) + conv_b1
  agg_kernel<<<N_NODES, 256, 0, stream>>>(Z1, wn, idxo, conv_b1, out1);
  // 7) BatchNorm (batch stats) + relu, in place
  bn_partial<<<256, 256, 0, stream>>>(out1, partial);
  bn_reduce<<<512, 256, 0, stream>>>(partial, colstats);
  bn_apply<<<N_NODES, 256, 0, stream>>>(out1, colstats, gamma, beta);
  // 8) Z2 = y @ conv_w2                                (4096 x 256)
  gemm_small<<<dim3(256 / 64, N_NODES / 64), 256, 0, stream>>>(
      out1, conv_w2, Z2, N_NODES, 256, 256);
  // 9) out = gather-agg(Z2) + conv_b2
  agg_kernel<<<N_NODES, 256, 0, stream>>>(Z2, wn, idxo, conv_b2, (float*)d_out);
}

// Round 2
// 792.462 us; speedup vs baseline: 2.2842x; 2.2842x over previous
//
#include <hip/hip_runtime.h>
#include <cfloat>

#define N_NODES 4096
#define C1_DIM  1001
#define D_DIM   4096
#define HMLP    1024
#define KCAT    (D_DIM + C1_DIM + 4)   // 5101
#define K1PAD   5120                   // padded, multiple of 32
#define TOPK    32

typedef unsigned short u16;
typedef __bf16 bf16x8 __attribute__((ext_vector_type(8)));
typedef u16    u16x8  __attribute__((ext_vector_type(8)));
typedef float  f32x4  __attribute__((ext_vector_type(4)));

__device__ __forceinline__ u16 f2bf(float f) {
  unsigned u = __float_as_uint(f);
  u += 0x7FFFu + ((u >> 16) & 1u);          // round-to-nearest-even
  return (u16)(u >> 16);
}
__device__ __forceinline__ float bf2f(u16 h) {
  return __uint_as_float(((unsigned)h) << 16);
}

__device__ __forceinline__ void gload16(const void* g, const void* l) {
  __builtin_amdgcn_global_load_lds(
      (const __attribute__((address_space(1))) unsigned int*)g,
      (__attribute__((address_space(3))) unsigned int*)l, 16, 0, 0);
}

// ---------------------------------------------------------------------------
// tail[n][c] = concat(probs, bbox, zeros) covering k-range 4096..5119
// ---------------------------------------------------------------------------
__global__ __launch_bounds__(256) void tail_build(
    const float* __restrict__ probs, const float* __restrict__ bbox,
    float* __restrict__ tail) {
  const int i = blockIdx.x * 256 + threadIdx.x;  // over N*1024
  const int n = i >> 10, c = i & 1023;
  float v = 0.f;
  if (c < C1_DIM)          v = probs[n * C1_DIM + c];
  else if (c < C1_DIM + 4) v = bbox[n * 4 + (c - C1_DIM)];
  tail[i] = v;
}

// ---------------------------------------------------------------------------
// out_hi/lo[C][Rpad] = split-bf16 transpose of in[R][C] (zero pad rows >= R)
// ---------------------------------------------------------------------------
__global__ __launch_bounds__(256) void transpose_split(
    const float* __restrict__ in, int R, int C, int Rpad,
    u16* __restrict__ out_hi, u16* __restrict__ out_lo) {
  __shared__ float t[64][65];
  const int rb = blockIdx.x * 64;     // input row (k) base
  const int cb = blockIdx.y * 64;     // input col (n) base
  const int tid = threadIdx.x;
  const int lr = tid >> 6, lc = tid & 63;
#pragma unroll
  for (int i = 0; i < 16; ++i) {
    const int r = lr + i * 4;
    const int gr = rb + r;
    t[r][lc] = (gr < R) ? in[(size_t)gr * C + cb + lc] : 0.f;
  }
  __syncthreads();
#pragma unroll
  for (int i = 0; i < 16; ++i) {
    const int c = lr + i * 4;                    // local n index
    const float v = t[lc][c];
    const u16 hi = f2bf(v);
    const u16 lo = f2bf(v - bf2f(hi));
    const size_t o = (size_t)(cb + c) * Rpad + rb + lc;
    out_hi[o] = hi; out_lo[o] = lo;
  }
}

// ---------------------------------------------------------------------------
// Split-bf16 MFMA GEMM. C = A(MxK) * Bt(NxK)^T + bias [, relu]
// AMODE 0: A as bf16 hi/lo planes (global_load_lds staging).
// AMODE 1: A as fp32 [query(4096) | tail(1024)], reg-staged + split.
// BM=128, BN=64, BK=32; 256 threads = 4 waves; wave tile 64x32.
// 3 MFMA products per fragment pair: hi*hi + hi*lo + lo*hi (~fp24).
// ---------------------------------------------------------------------------
template<int AMODE, bool RELU, bool OUT_SPLIT>
__global__ __launch_bounds__(256, 2) void gemm_mfma(
    const u16* __restrict__ Ahi, const u16* __restrict__ Alo,
    const float* __restrict__ Aq, const float* __restrict__ Atail,
    const u16* __restrict__ Bthi, const u16* __restrict__ Btlo,
    const float* __restrict__ bias,
    float* __restrict__ Cf, u16* __restrict__ Chi, u16* __restrict__ Clo,
    int M, int N, int K) {
  __shared__ u16 lAhi[128 * 32], lAlo[128 * 32];
  __shared__ u16 lBhi[64 * 32],  lBlo[64 * 32];
  const int tid  = threadIdx.x;
  const int lane = tid & 63, wave = tid >> 6;
  const int row0 = blockIdx.y * 128, col0 = blockIdx.x * 64;
  const int wr0 = (wave >> 1) * 64;   // 0 or 64
  const int wc0 = (wave & 1) * 32;    // 0 or 32

  f32x4 acc[4][2];
#pragma unroll
  for (int mi = 0; mi < 4; ++mi)
#pragma unroll
    for (int ni = 0; ni < 2; ++ni) acc[mi][ni] = (f32x4){0.f, 0.f, 0.f, 0.f};

  const int srow = tid >> 2;          // staging row 0..63
  const int skof = (tid & 3) * 8;     // staging k offset
  const int wubase = (tid & ~63) * 8; // wave-uniform LDS slot base (u16 units)

  for (int k0 = 0; k0 < K; k0 += 32) {
    if (AMODE == 1) {
      float4 x0[2], x1[2];
#pragma unroll
      for (int j = 0; j < 2; ++j) {
        const int grow = row0 + srow + j * 64;
        const float* src = (k0 < D_DIM)
            ? Aq    + (size_t)grow * D_DIM + k0 + skof
            : Atail + (size_t)grow * 1024 + (k0 - D_DIM) + skof;
        x0[j] = *(const float4*)src;
        x1[j] = *(const float4*)(src + 4);
      }
      __syncthreads();   // previous compute done
      gload16(Bthi + (size_t)(col0 + srow) * K + k0 + skof, &lBhi[wubase]);
      gload16(Btlo + (size_t)(col0 + srow) * K + k0 + skof, &lBlo[wubase]);
#pragma unroll
      for (int j = 0; j < 2; ++j) {
        float xs[8] = {x0[j].x, x0[j].y, x0[j].z, x0[j].w,
                       x1[j].x, x1[j].y, x1[j].z, x1[j].w};
        u16x8 hi, lo;
#pragma unroll
        for (int e = 0; e < 8; ++e) {
          const u16 h = f2bf(xs[e]);
          hi[e] = h;
          lo[e] = f2bf(xs[e] - bf2f(h));
        }
        *(u16x8*)&lAhi[(srow + j * 64) * 32 + skof] = hi;
        *(u16x8*)&lAlo[(srow + j * 64) * 32 + skof] = lo;
      }
      __syncthreads();   // drains lgkm + vmcnt before compute
    } else {
      __syncthreads();   // previous compute done
      gload16(Ahi + (size_t)(row0 + srow) * K + k0 + skof,      &lAhi[wubase]);
      gload16(Ahi + (size_t)(row0 + srow + 64) * K + k0 + skof, &lAhi[wubase + 256 * 8]);
      gload16(Alo + (size_t)(row0 + srow) * K + k0 + skof,      &lAlo[wubase]);
      gload16(Alo + (size_t)(row0 + srow + 64) * K + k0 + skof, &lAlo[wubase + 256 * 8]);
      gload16(Bthi + (size_t)(col0 + srow) * K + k0 + skof, &lBhi[wubase]);
      gload16(Btlo + (size_t)(col0 + srow) * K + k0 + skof, &lBlo[wubase]);
      __syncthreads();   // drains gload_lds queue before compute
    }

    const int ko = (lane >> 4) * 8;
    const int ar = lane & 15;
    bf16x8 ah[4], al[4], bh[2], bl[2];
#pragma unroll
    for (int mi = 0; mi < 4; ++mi) {
      const int r = wr0 + mi * 16 + ar;
      ah[mi] = *(const bf16x8*)&lAhi[r * 32 + ko];
      al[mi] = *(const bf16x8*)&lAlo[r * 32 + ko];
    }
#pragma unroll
    for (int ni = 0; ni < 2; ++ni) {
      const int c = wc0 + ni * 16 + ar;
      bh[ni] = *(const bf16x8*)&lBhi[c * 32 + ko];
      bl[ni] = *(const bf16x8*)&lBlo[c * 32 + ko];
    }
#pragma unroll
    for (int mi = 0; mi < 4; ++mi)
#pragma unroll
      for (int ni = 0; ni < 2; ++ni) {
        acc[mi][ni] = __builtin_amdgcn_mfma_f32_16x16x32_bf16(ah[mi], bh[ni], acc[mi][ni], 0, 0, 0);
        acc[mi][ni] = __builtin_amdgcn_mfma_f32_16x16x32_bf16(ah[mi], bl[ni], acc[mi][ni], 0, 0, 0);
        acc[mi][ni] = __builtin_amdgcn_mfma_f32_16x16x32_bf16(al[mi], bh[ni], acc[mi][ni], 0, 0, 0);
      }
  }

#pragma unroll
  for (int mi = 0; mi < 4; ++mi)
#pragma unroll
    for (int ni = 0; ni < 2; ++ni) {
      const int gcol = col0 + wc0 + ni * 16 + (lane & 15);
      const float b = bias[gcol];
#pragma unroll
      for (int r = 0; r < 4; ++r) {
        const int grow = row0 + wr0 + mi * 16 + (lane >> 4) * 4 + r;
        float v = acc[mi][ni][r] + b;
        if (RELU) v = fmaxf(v, 0.f);
        if (OUT_SPLIT) {
          const u16 hi = f2bf(v);
          Chi[(size_t)grow * N + gcol] = hi;
          Clo[(size_t)grow * N + gcol] = f2bf(v - bf2f(hi));
        } else {
          Cf[(size_t)grow * N + gcol] = v;
        }
      }
    }
}

// ---------------------------------------------------------------------------
// Small fp32 GEMM (conv path): 64x64 tile, BK=16, 256 threads, 4x4/thread.
// ---------------------------------------------------------------------------
__global__ __launch_bounds__(256) void gemm_small(
    const float* __restrict__ A, const float* __restrict__ B,
    float* __restrict__ C, int M, int Ncols, int K) {
  __shared__ float As[16][68];
  __shared__ float Bs[16][68];
  const int tid = threadIdx.x;
  const int row0 = blockIdx.y * 64, col0 = blockIdx.x * 64;
  const int tx = tid & 15, ty = tid >> 4;
  const int arow = tid >> 2, acol = (tid & 3) * 4;
  const int brow = tid >> 4, bcol = (tid & 15) * 4;

  float acc[4][4];
#pragma unroll
  for (int i = 0; i < 4; ++i)
#pragma unroll
    for (int j = 0; j < 4; ++j) acc[i][j] = 0.f;

  for (int k0 = 0; k0 < K; k0 += 16) {
    const float4 a4 = *(const float4*)(A + (size_t)(row0 + arow) * K + k0 + acol);
    const float4 b4 = *(const float4*)(B + (size_t)(k0 + brow) * Ncols + col0 + bcol);
    __syncthreads();
    As[acol + 0][arow] = a4.x; As[acol + 1][arow] = a4.y;
    As[acol + 2][arow] = a4.z; As[acol + 3][arow] = a4.w;
    *(float4*)&Bs[brow][bcol] = b4;
    __syncthreads();
#pragma unroll
    for (int k = 0; k < 16; ++k) {
      float av[4], bw[4];
      *(float4*)&av[0] = *(const float4*)&As[k][ty * 4];
      *(float4*)&bw[0] = *(const float4*)&Bs[k][tx * 4];
#pragma unroll
      for (int i = 0; i < 4; ++i)
#pragma unroll
        for (int j = 0; j < 4; ++j) acc[i][j] += av[i] * bw[j];
    }
  }

#pragma unroll
  for (int i = 0; i < 4; ++i) {
    const int r = row0 + ty * 4 + i;
    float4 v;
    v.x = acc[i][0]; v.y = acc[i][1]; v.z = acc[i][2]; v.w = acc[i][3];
    *(float4*)(C + (size_t)r * Ncols + col0 + tx * 4) = v;
  }
}

// ---------------------------------------------------------------------------
// Top-K: one block per row; 32 iterative argmax passes over LDS row.
// ---------------------------------------------------------------------------
__global__ __launch_bounds__(256) void topk_kernel(
    const float* __restrict__ adj, float* __restrict__ vals,
    int* __restrict__ idxo, float* __restrict__ dinv) {
  __shared__ float sv[N_NODES];
  __shared__ float rv[256];
  __shared__ int   ri[256];
  const int n = blockIdx.x, tid = threadIdx.x;
  const float4* rowp = (const float4*)(adj + (size_t)n * N_NODES);
  for (int j = tid; j < N_NODES / 4; j += 256)
    *(float4*)&sv[j * 4] = rowp[j];
  __syncthreads();

  float sum = 0.f;
  for (int it = 0; it < TOPK; ++it) {
    float best = -FLT_MAX; int bi = N_NODES;
    for (int j = tid; j < N_NODES; j += 256) {
      const float v = sv[j];
      if (v > best) { best = v; bi = j; }
    }
    rv[tid] = best; ri[tid] = bi;
    __syncthreads();
    for (int s = 128; s > 0; s >>= 1) {
      if (tid < s) {
        const float ov = rv[tid + s]; const int oi = ri[tid + s];
        if (ov > rv[tid] || (ov == rv[tid] && oi < ri[tid])) { rv[tid] = ov; ri[tid] = oi; }
      }
      __syncthreads();
    }
    if (tid == 0) {
      vals[(size_t)n * TOPK + it] = rv[0];
      idxo[(size_t)n * TOPK + it] = ri[0];
      sv[ri[0]] = -FLT_MAX;
      sum += rv[0];
    }
    __syncthreads();
  }
  if (tid == 0)
    dinv[n] = (sum > 0.f) ? rsqrtf(fmaxf(sum, 1e-12f)) : 0.f;
}

__global__ void wn_kernel(const float* __restrict__ vals, const int* __restrict__ idxo,
                          const float* __restrict__ dinv, float* __restrict__ wn) {
  const int i = blockIdx.x * 256 + threadIdx.x;
  const int n = i >> 5;
  wn[i] = vals[i] * dinv[n] * dinv[idxo[i]];
}

__global__ __launch_bounds__(256) void agg_kernel(
    const float* __restrict__ Z, const float* __restrict__ wn,
    const int* __restrict__ idxo, const float* __restrict__ bias,
    float* __restrict__ out) {
  const int n = blockIdx.x, f = threadIdx.x;
  float acc = bias[f];
#pragma unroll
  for (int k = 0; k < TOPK; ++k) {
    const float w = wn[n * TOPK + k];
    const int   j = idxo[n * TOPK + k];
    acc += w * Z[(size_t)j * 256 + f];
  }
  out[(size_t)n * 256 + f] = acc;
}

__global__ __launch_bounds__(256) void bn_partial(
    const float* __restrict__ x, float* __restrict__ partial) {
  const int b = blockIdx.x, c = threadIdx.x;
  float s = 0.f, s2 = 0.f;
  for (int r = b * 16; r < b * 16 + 16; ++r) {
    const float v = x[(size_t)r * 256 + c];
    s += v; s2 += v * v;
  }
  partial[(size_t)b * 512 + c]       = s;
  partial[(size_t)b * 512 + 256 + c] = s2;
}

__global__ __launch_bounds__(256) void bn_reduce(
    const float* __restrict__ partial, float* __restrict__ colstats) {
  const int j = blockIdx.x, t = threadIdx.x;
  __shared__ float red[256];
  red[t] = partial[(size_t)t * 512 + j];
  __syncthreads();
  for (int s = 128; s > 0; s >>= 1) {
    if (t < s) red[t] += red[t + s];
    __syncthreads();
  }
  if (t == 0) colstats[j] = red[0];
}

__global__ __launch_bounds__(256) void bn_apply(
    float* __restrict__ x, const float* __restrict__ colstats,
    const float* __restrict__ gamma, const float* __restrict__ beta) {
  const int i = blockIdx.x * 256 + threadIdx.x;
  const int c = i & 255;
  const float mean = colstats[c] * (1.f / 4096.f);
  float var = colstats[256 + c] * (1.f / 4096.f) - mean * mean;
  var = fmaxf(var, 0.f);
  const float v = (x[i] - mean) * rsqrtf(var + 1e-5f) * gamma[c] + beta[c];
  x[i] = fmaxf(v, 0.f);
}

// ---------------------------------------------------------------------------
extern "C" void kernel_launch(void* const* d_in, const int* in_sizes, int n_in,
                              void* d_out, int out_size, void* d_ws, size_t ws_size,
                              hipStream_t stream) {
  const float* probs   = (const float*)d_in[0];
  const float* bbox    = (const float*)d_in[1];
  const float* query   = (const float*)d_in[2];
  const float* node    = (const float*)d_in[3];
  const float* mlp_w1  = (const float*)d_in[4];
  const float* mlp_b1  = (const float*)d_in[5];
  const float* mlp_w2  = (const float*)d_in[6];
  const float* mlp_b2  = (const float*)d_in[7];
  const float* conv_w1 = (const float*)d_in[8];
  const float* conv_b1 = (const float*)d_in[9];
  const float* conv_w2 = (const float*)d_in[10];
  const float* conv_b2 = (const float*)d_in[11];
  const float* gamma   = (const float*)d_in[12];
  const float* beta    = (const float*)d_in[13];

  float* ws = (float*)d_ws;
  size_t off = 0;
  float* adj  = ws + off;  off += (size_t)N_NODES * N_NODES;   // 16.78M f
  float* tail = ws + off;  off += (size_t)N_NODES * 1024;      // 4.19M f
  u16* w1t_hi = (u16*)(ws + off);                              // [1024][5120] u16
  u16* w1t_lo = w1t_hi + (size_t)HMLP * K1PAD;
  off += (size_t)HMLP * K1PAD;                                 // 2 u16 planes = 5.24M f
  u16* h_hi = (u16*)(ws + off);                                // [4096][1024] u16
  u16* h_lo = h_hi + (size_t)N_NODES * HMLP;
  off += (size_t)N_NODES * HMLP;                               // 2 u16 planes = 4.19M f
  float* vals = ws + off;  off += (size_t)N_NODES * TOPK;
  int*   idxo = (int*)(ws + off); off += (size_t)N_NODES * TOPK;
  float* wn   = ws + off;  off += (size_t)N_NODES * TOPK;
  float* dinv = ws + off;  off += N_NODES;
  // W2t overlays the (dead after GEMM1) W1t region: [4096][1024] u16 x2
  u16* w2t_hi = w1t_hi;
  u16* w2t_lo = w2t_hi + (size_t)N_NODES * HMLP;
  // conv-stage buffers overlay the (dead after GEMM1) tail region
  float* Z1       = tail;
  float* out1     = tail + (size_t)N_NODES * 256;
  float* Z2       = tail + (size_t)N_NODES * 512;
  float* partial  = tail + (size_t)N_NODES * 768;
  float* colstats = partial + 256 * 512;

  // 1) tail = [probs | bbox | 0]                        (4096 x 1024)
  tail_build<<<(N_NODES * 1024) / 256, 256, 0, stream>>>(probs, bbox, tail);
  // 2) W1t hi/lo = split-transpose(mlp_w1)              (1024 x 5120)
  transpose_split<<<dim3(K1PAD / 64, HMLP / 64), 256, 0, stream>>>(
      mlp_w1, KCAT, HMLP, K1PAD, w1t_hi, w1t_lo);
  // 3) h = relu(concat @ W1 + b1) -> bf16 hi/lo         (4096 x 1024)
  gemm_mfma<1, true, true><<<dim3(HMLP / 64, N_NODES / 128), 256, 0, stream>>>(
      nullptr, nullptr, query, tail, w1t_hi, w1t_lo, mlp_b1,
      nullptr, h_hi, h_lo, N_NODES, HMLP, K1PAD);
  // 4) W2t hi/lo = split-transpose(mlp_w2)              (4096 x 1024)
  transpose_split<<<dim3(HMLP / 64, N_NODES / 64), 256, 0, stream>>>(
      mlp_w2, HMLP, N_NODES, HMLP, w2t_hi, w2t_lo);
  // 5) adj = h @ W2 + b2 (fp32 out)                     (4096 x 4096)
  gemm_mfma<0, false, false><<<dim3(N_NODES / 64, N_NODES / 128), 256, 0, stream>>>(
      h_hi, h_lo, nullptr, nullptr, w2t_hi, w2t_lo, mlp_b2,
      adj, nullptr, nullptr, N_NODES, N_NODES, HMLP);
  // 6) top-32 per row + dinv
  topk_kernel<<<N_NODES, 256, 0, stream>>>(adj, vals, idxo, dinv);
  // 7) wn
  wn_kernel<<<(N_NODES * TOPK) / 256, 256, 0, stream>>>(vals, idxo, dinv, wn);
  // 8) Z1 = node_emb @ conv_w1 (fp32)                   (4096 x 256)
  gemm_small<<<dim3(256 / 64, N_NODES / 64), 256, 0, stream>>>(
      node, conv_w1, Z1, N_NODES, 256, D_DIM);
  // 9) out1 = gather-agg(Z1) + conv_b1
  agg_kernel<<<N_NODES, 256, 0, stream>>>(Z1, wn, idxo, conv_b1, out1);
  // 10) BatchNorm (batch stats) + relu, in place
  bn_partial<<<256, 256, 0, stream>>>(out1, partial);
  bn_reduce<<<512, 256, 0, stream>>>(partial, colstats);
  bn_apply<<<N_NODES, 256, 0, stream>>>(out1, colstats, gamma, beta);
  // 11) Z2 = y @ conv_w2 (fp32)                         (4096 x 256)
  gemm_small<<<dim3(256 / 64, N_NODES / 64), 256, 0, stream>>>(
      out1, conv_w2, Z2, N_NODES, 256, 256);
  // 12) out = gather-agg(Z2) + conv_b2
  agg_kernel<<<N_NODES, 256, 0, stream>>>(Z2, wn, idxo, conv_b2, (float*)d_out);
}

// Round 4
// 642.684 us; speedup vs baseline: 2.8166x; 1.2331x over previous
//
#include <hip/hip_runtime.h>
#include <cfloat>

#define N_NODES 4096
#define C1_DIM  1001
#define D_DIM   4096
#define HMLP    1024
#define KCAT    (D_DIM + C1_DIM + 4)   // 5101
#define K1PAD   5120                   // padded, multiple of 32
#define TOPK    32

typedef unsigned short u16;
typedef __bf16 bf16x8 __attribute__((ext_vector_type(8)));
typedef u16    u16x8  __attribute__((ext_vector_type(8)));
typedef float  f32x4  __attribute__((ext_vector_type(4)));

__device__ __forceinline__ u16 f2bf(float f) {
  unsigned u = __float_as_uint(f);
  u += 0x7FFFu + ((u >> 16) & 1u);          // round-to-nearest-even
  return (u16)(u >> 16);
}
__device__ __forceinline__ float bf2f(u16 h) {
  return __uint_as_float(((unsigned)h) << 16);
}

__device__ __forceinline__ void gload16(const void* g, void* l) {
  __builtin_amdgcn_global_load_lds(
      (const __attribute__((address_space(1))) unsigned int*)g,
      (__attribute__((address_space(3))) unsigned int*)l, 16, 0, 0);
}

// ---------------------------------------------------------------------------
// out_hi/lo[C][Rpad] = split-bf16 transpose of in[R][C] (zero pad rows >= R)
// ---------------------------------------------------------------------------
__global__ __launch_bounds__(256) void transpose_split(
    const float* __restrict__ in, int R, int C, int Rpad,
    u16* __restrict__ out_hi, u16* __restrict__ out_lo) {
  __shared__ float t[64][65];
  const int rb = blockIdx.x * 64;     // input row (k) base
  const int cb = blockIdx.y * 64;     // input col (n) base
  const int tid = threadIdx.x;
  const int lr = tid >> 6, lc = tid & 63;
#pragma unroll
  for (int i = 0; i < 16; ++i) {
    const int r = lr + i * 4;
    const int gr = rb + r;
    t[r][lc] = (gr < R) ? in[(size_t)gr * C + cb + lc] : 0.f;
  }
  __syncthreads();
#pragma unroll
  for (int i = 0; i < 16; ++i) {
    const int c = lr + i * 4;                    // local n index
    const float v = t[lc][c];
    const u16 hi = f2bf(v);
    const u16 lo = f2bf(v - bf2f(hi));
    const size_t o = (size_t)(cb + c) * Rpad + rb + lc;
    out_hi[o] = hi; out_lo[o] = lo;
  }
}

// ---------------------------------------------------------------------------
// Split-bf16 MFMA GEMM body.  C = A(MxK) * Bt(NxK)^T [+ bias][, relu]
// AMODE 0: A as bf16 hi/lo planes (global_load_lds staging).
// AMODE 1: A as fp32 [Aq (D_DIM wide) | probs|bbox|0 for k>=D_DIM],
//          reg-staged + split in-kernel. (K<=D_DIM never touches the tail.)
// BM=128, BN=64, BK=32; 256 threads = 4 waves; wave tile 64x32.
// Double-buffered LDS with next-tile prefetch; ONE barrier per K-step.
// LDS per buffer (u16 units): Ahi@0 [128*32], Alo@4096, Bhi@8192 [64*32],
// Blo@10240; buffer stride 12288 u16 (24 KB); total 48 KB.
// ---------------------------------------------------------------------------
template<int AMODE, bool RELU, bool OUT_SPLIT, bool HASBIAS>
__device__ __forceinline__ void gemm_body(
    int bx, int by,
    const u16* __restrict__ Ahi, const u16* __restrict__ Alo,
    const float* __restrict__ Aq,
    const float* __restrict__ probs, const float* __restrict__ bbox,
    const u16* __restrict__ Bthi, const u16* __restrict__ Btlo,
    const float* __restrict__ bias,
    float* __restrict__ Cf, u16* __restrict__ Chi, u16* __restrict__ Clo,
    int N, int K, u16* lds) {
  const int tid = threadIdx.x;
  const int lane = tid & 63, wave = tid >> 6;
  const int row0 = by * 128, col0 = bx * 64;
  const int wr0 = (wave >> 1) * 64, wc0 = (wave & 1) * 32;
  const int srow = tid >> 2, skof = (tid & 3) * 8;
  const int wu = (tid & ~63) * 8;      // wave-uniform base within a plane (u16)

  f32x4 acc[4][2];
#pragma unroll
  for (int mi = 0; mi < 4; ++mi)
#pragma unroll
    for (int ni = 0; ni < 2; ++ni) acc[mi][ni] = (f32x4){0.f, 0.f, 0.f, 0.f};

  auto stageB = [&](int buf, int k0) {
    u16* base = lds + buf * 12288;
    gload16(Bthi + (size_t)(col0 + srow) * K + k0 + skof, base + 8192 + wu);
    gload16(Btlo + (size_t)(col0 + srow) * K + k0 + skof, base + 10240 + wu);
  };
  auto stageA0 = [&](int buf, int k0) {
    u16* base = lds + buf * 12288;
    gload16(Ahi + (size_t)(row0 + srow) * K + k0 + skof,      base + wu);
    gload16(Ahi + (size_t)(row0 + 64 + srow) * K + k0 + skof, base + 2048 + wu);
    gload16(Alo + (size_t)(row0 + srow) * K + k0 + skof,      base + 4096 + wu);
    gload16(Alo + (size_t)(row0 + 64 + srow) * K + k0 + skof, base + 6144 + wu);
  };
  auto loadA1 = [&](int k0, float4* x) {
    const int kk = k0 + skof;
#pragma unroll
    for (int j = 0; j < 2; ++j) {
      const int grow = row0 + srow + j * 64;
      if (kk < D_DIM) {
        const float* src = Aq + (size_t)grow * D_DIM + kk;
        x[j * 2]     = *(const float4*)src;
        x[j * 2 + 1] = *(const float4*)(src + 4);
      } else {
        float v[8];
#pragma unroll
        for (int e = 0; e < 8; ++e) {
          const int c = kk + e - D_DIM;
          v[e] = (c < C1_DIM) ? probs[(size_t)grow * C1_DIM + c]
               : (c < C1_DIM + 4) ? bbox[(size_t)grow * 4 + (c - C1_DIM)] : 0.f;
        }
        x[j * 2]     = make_float4(v[0], v[1], v[2], v[3]);
        x[j * 2 + 1] = make_float4(v[4], v[5], v[6], v[7]);
      }
    }
  };
  auto writeA1 = [&](int buf, const float4* x) {
    u16* base = lds + buf * 12288;
#pragma unroll
    for (int j = 0; j < 2; ++j) {
      const float xs[8] = {x[j*2].x, x[j*2].y, x[j*2].z, x[j*2].w,
                           x[j*2+1].x, x[j*2+1].y, x[j*2+1].z, x[j*2+1].w};
      u16x8 hi, lo;
#pragma unroll
      for (int e = 0; e < 8; ++e) {
        const u16 hh = f2bf(xs[e]);
        hi[e] = hh;
        lo[e] = f2bf(xs[e] - bf2f(hh));
      }
      *(u16x8*)&base[(srow + j * 64) * 32 + skof] = hi;
      *(u16x8*)&base[4096 + (srow + j * 64) * 32 + skof] = lo;
    }
  };
  auto compute = [&](int buf) {
    u16* base = lds + buf * 12288;
    const int ko = (lane >> 4) * 8;
    const int ar = lane & 15;
    bf16x8 ah[4], al[4], bh[2], bl[2];
#pragma unroll
    for (int mi = 0; mi < 4; ++mi) {
      const int r = wr0 + mi * 16 + ar;
      ah[mi] = *(const bf16x8*)&base[r * 32 + ko];
      al[mi] = *(const bf16x8*)&base[4096 + r * 32 + ko];
    }
#pragma unroll
    for (int ni = 0; ni < 2; ++ni) {
      const int c = wc0 + ni * 16 + ar;
      bh[ni] = *(const bf16x8*)&base[8192 + c * 32 + ko];
      bl[ni] = *(const bf16x8*)&base[10240 + c * 32 + ko];
    }
#pragma unroll
    for (int mi = 0; mi < 4; ++mi)
#pragma unroll
      for (int ni = 0; ni < 2; ++ni) {
        acc[mi][ni] = __builtin_amdgcn_mfma_f32_16x16x32_bf16(ah[mi], bh[ni], acc[mi][ni], 0, 0, 0);
        acc[mi][ni] = __builtin_amdgcn_mfma_f32_16x16x32_bf16(ah[mi], bl[ni], acc[mi][ni], 0, 0, 0);
        acc[mi][ni] = __builtin_amdgcn_mfma_f32_16x16x32_bf16(al[mi], bh[ni], acc[mi][ni], 0, 0, 0);
      }
  };

  int cur = 0;
  if (AMODE == 0) {
    stageA0(0, 0); stageB(0, 0);
    __syncthreads();                       // drains vmcnt: buf0 ready
    for (int k0 = 0; k0 < K; k0 += 32) {
      if (k0 + 32 < K) { stageA0(cur ^ 1, k0 + 32); stageB(cur ^ 1, k0 + 32); }
      compute(cur);
      __syncthreads();                     // drain prefetch + sync readers
      cur ^= 1;
    }
  } else {
    float4 x[4];
    loadA1(0, x); stageB(0, 0); writeA1(0, x);
    __syncthreads();
    for (int k0 = 0; k0 < K; k0 += 32) {
      const bool nx = (k0 + 32 < K);
      float4 xn[4];
      if (nx) { loadA1(k0 + 32, xn); stageB(cur ^ 1, k0 + 32); }
      compute(cur);
      if (nx) writeA1(cur ^ 1, xn);        // load latency hidden under MFMA
      __syncthreads();
      cur ^= 1;
    }
  }

#pragma unroll
  for (int mi = 0; mi < 4; ++mi)
#pragma unroll
    for (int ni = 0; ni < 2; ++ni) {
      const int gcol = col0 + wc0 + ni * 16 + (lane & 15);
      const float b = HASBIAS ? bias[gcol] : 0.f;
#pragma unroll
      for (int r = 0; r < 4; ++r) {
        const int grow = row0 + wr0 + mi * 16 + (lane >> 4) * 4 + r;
        float v = acc[mi][ni][r] + b;
        if (RELU) v = fmaxf(v, 0.f);
        if (OUT_SPLIT) {
          const u16 hi = f2bf(v);
          Chi[(size_t)grow * N + gcol] = hi;
          Clo[(size_t)grow * N + gcol] = f2bf(v - bf2f(hi));
        } else {
          Cf[(size_t)grow * N + gcol] = v;
        }
      }
    }
}

// GEMM1 standalone: h = relu(concat @ W1 + b1) -> bf16 hi/lo planes
__global__ __launch_bounds__(256, 2) void gemm1_kernel(
    const float* __restrict__ query, const float* __restrict__ probs,
    const float* __restrict__ bbox,
    const u16* __restrict__ w1t_hi, const u16* __restrict__ w1t_lo,
    const float* __restrict__ b1,
    u16* __restrict__ h_hi, u16* __restrict__ h_lo) {
  __shared__ u16 lds[2 * 12288];
  gemm_body<1, true, true, true>(blockIdx.x, blockIdx.y,
      nullptr, nullptr, query, probs, bbox, w1t_hi, w1t_lo, b1,
      nullptr, h_hi, h_lo, HMLP, K1PAD, lds);
}

// Fused: Z1 (128 long blocks first) + GEMM2/adj (2048 blocks)
__global__ __launch_bounds__(256, 2) void fused2_kernel(
    const u16* __restrict__ h_hi, const u16* __restrict__ h_lo,
    const u16* __restrict__ w2t_hi, const u16* __restrict__ w2t_lo,
    const float* __restrict__ b2, float* __restrict__ adj,
    const float* __restrict__ node,
    const u16* __restrict__ w1ct_hi, const u16* __restrict__ w1ct_lo,
    float* __restrict__ Z1) {
  __shared__ u16 lds[2 * 12288];
  const int bid = blockIdx.x;
  if (bid < 128) {          // Z1 = node @ conv_w1 (fp32 out, no bias)
    gemm_body<1, false, false, false>(bid & 3, bid >> 2,
        nullptr, nullptr, node, nullptr, nullptr, w1ct_hi, w1ct_lo, nullptr,
        Z1, nullptr, nullptr, 256, D_DIM, lds);
  } else {                  // adj = h @ W2 + b2 (fp32 out)
    const int r = bid - 128;
    gemm_body<0, false, false, true>(r & 63, r >> 6,
        h_hi, h_lo, nullptr, nullptr, nullptr, w2t_hi, w2t_lo, b2,
        adj, nullptr, nullptr, N_NODES, HMLP, lds);
  }
}

// ---------------------------------------------------------------------------
// Small fp32 GEMM (Z2 only): 64x64 tile, BK=16, 256 threads, 4x4/thread.
// ---------------------------------------------------------------------------
__global__ __launch_bounds__(256) void gemm_small(
    const float* __restrict__ A, const float* __restrict__ B,
    float* __restrict__ C, int M, int Ncols, int K) {
  __shared__ float As[16][68];
  __shared__ float Bs[16][68];
  const int tid = threadIdx.x;
  const int row0 = blockIdx.y * 64, col0 = blockIdx.x * 64;
  const int tx = tid & 15, ty = tid >> 4;
  const int arow = tid >> 2, acol = (tid & 3) * 4;
  const int brow = tid >> 4, bcol = (tid & 15) * 4;

  float acc[4][4];
#pragma unroll
  for (int i = 0; i < 4; ++i)
#pragma unroll
    for (int j = 0; j < 4; ++j) acc[i][j] = 0.f;

  for (int k0 = 0; k0 < K; k0 += 16) {
    const float4 a4 = *(const float4*)(A + (size_t)(row0 + arow) * K + k0 + acol);
    const float4 b4 = *(const float4*)(B + (size_t)(k0 + brow) * Ncols + col0 + bcol);
    __syncthreads();
    As[acol + 0][arow] = a4.x; As[acol + 1][arow] = a4.y;
    As[acol + 2][arow] = a4.z; As[acol + 3][arow] = a4.w;
    *(float4*)&Bs[brow][bcol] = b4;
    __syncthreads();
#pragma unroll
    for (int k = 0; k < 16; ++k) {
      float av[4], bw[4];
      *(float4*)&av[0] = *(const float4*)&As[k][ty * 4];
      *(float4*)&bw[0] = *(const float4*)&Bs[k][tx * 4];
#pragma unroll
      for (int i = 0; i < 4; ++i)
#pragma unroll
        for (int j = 0; j < 4; ++j) acc[i][j] += av[i] * bw[j];
    }
  }

#pragma unroll
  for (int i = 0; i < 4; ++i) {
    const int r = row0 + ty * 4 + i;
    float4 v;
    v.x = acc[i][0]; v.y = acc[i][1]; v.z = acc[i][2]; v.w = acc[i][3];
    *(float4*)(C + (size_t)r * Ncols + col0 + tx * 4) = v;
  }
}

// ---------------------------------------------------------------------------
// Top-K: one block/row. Per-thread cached argmax over its 16 elements
// (strided float4 groups, LDS-resident row); per pass: 64-lane shfl_xor
// butterfly + 4-way cross-wave reduce; only the winner thread rescans.
// Tie -> lowest index (matches jax.lax.top_k). 2 barriers per pass.
// ---------------------------------------------------------------------------
__global__ __launch_bounds__(256) void topk_kernel(
    const float* __restrict__ adj, float* __restrict__ vals,
    int* __restrict__ idxo, float* __restrict__ dinv) {
  __shared__ float sv[N_NODES];
  __shared__ float rw[4];
  __shared__ int   iw[4];
  const int n = blockIdx.x, tid = threadIdx.x;
  const int lane = tid & 63, wave = tid >> 6;
  const float4* rowp = (const float4*)(adj + (size_t)n * N_NODES);

  float mv = -FLT_MAX; int mi = 0x7FFFFFFF;
  for (int g = tid; g < N_NODES / 4; g += 256) {
    const float4 v4 = rowp[g];
    *(float4*)&sv[g * 4] = v4;
    if (v4.x > mv) { mv = v4.x; mi = g * 4 + 0; }
    if (v4.y > mv) { mv = v4.y; mi = g * 4 + 1; }
    if (v4.z > mv) { mv = v4.z; mi = g * 4 + 2; }
    if (v4.w > mv) { mv = v4.w; mi = g * 4 + 3; }
  }

  float sum = 0.f;
  for (int it = 0; it < TOPK; ++it) {
    float bv = mv; int bi = mi;
#pragma unroll
    for (int off = 1; off < 64; off <<= 1) {
      const float ov = __shfl_xor(bv, off);
      const int   oi = __shfl_xor(bi, off);
      if (ov > bv || (ov == bv && oi < bi)) { bv = ov; bi = oi; }
    }
    if (lane == 0) { rw[wave] = bv; iw[wave] = bi; }
    __syncthreads();
    bv = rw[0]; bi = iw[0];
#pragma unroll
    for (int w = 1; w < 4; ++w) {
      const float ov = rw[w]; const int oi = iw[w];
      if (ov > bv || (ov == bv && oi < bi)) { bv = ov; bi = oi; }
    }
    if (tid == 0) {
      vals[(size_t)n * TOPK + it] = bv;
      idxo[(size_t)n * TOPK + it] = bi;
    }
    sum += bv;
    if (tid == ((bi >> 2) & 255)) {        // owner removes + rescans its 16
      sv[bi] = -FLT_MAX;
      mv = -FLT_MAX; mi = 0x7FFFFFFF;
      for (int g = tid; g < N_NODES / 4; g += 256) {
#pragma unroll
        for (int e = 0; e < 4; ++e) {
          const float v = sv[g * 4 + e];
          if (v > mv) { mv = v; mi = g * 4 + e; }
        }
      }
    }
    __syncthreads();                        // protect rw/iw for next pass
  }
  if (tid == 0)
    dinv[n] = (sum > 0.f) ? rsqrtf(fmaxf(sum, 1e-12f)) : 0.f;
}

// out[n,f] = bias[f] + sum_k vals[n,k]*dinv[n]*dinv[idx]*Z[idx[n,k], f]
__global__ __launch_bounds__(256) void agg_kernel(
    const float* __restrict__ Z, const float* __restrict__ vals,
    const int* __restrict__ idxo, const float* __restrict__ dinv,
    const float* __restrict__ bias, float* __restrict__ out) {
  const int n = blockIdx.x, f = threadIdx.x;
  const float dn = dinv[n];
  float acc = bias[f];
#pragma unroll
  for (int k = 0; k < TOPK; ++k) {
    const int   j = idxo[n * TOPK + k];
    const float w = vals[n * TOPK + k] * dn * dinv[j];
    acc += w * Z[(size_t)j * 256 + f];
  }
  out[(size_t)n * 256 + f] = acc;
}

// BatchNorm stats: 128 partial slabs of 32 rows, then tree reduce.
__global__ __launch_bounds__(256) void bn_partial(
    const float* __restrict__ x, float* __restrict__ partial) {
  const int b = blockIdx.x, c = threadIdx.x;
  float s = 0.f, s2 = 0.f;
  for (int r = b * 32; r < b * 32 + 32; ++r) {
    const float v = x[(size_t)r * 256 + c];
    s += v; s2 += v * v;
  }
  partial[(size_t)b * 512 + c]       = s;
  partial[(size_t)b * 512 + 256 + c] = s2;
}

__global__ __launch_bounds__(256) void bn_reduce(
    const float* __restrict__ partial, float* __restrict__ colstats) {
  const int j = blockIdx.x, t = threadIdx.x;
  __shared__ float red[128];
  if (t < 128) red[t] = partial[(size_t)t * 512 + j];
  __syncthreads();
  for (int s = 64; s > 0; s >>= 1) {
    if (t < s) red[t] += red[t + s];
    __syncthreads();
  }
  if (t == 0) colstats[j] = red[0];
}

__global__ __launch_bounds__(256) void bn_apply(
    float* __restrict__ x, const float* __restrict__ colstats,
    const float* __restrict__ gamma, const float* __restrict__ beta) {
  const int i = blockIdx.x * 256 + threadIdx.x;
  const int c = i & 255;
  const float mean = colstats[c] * (1.f / 4096.f);
  float var = colstats[256 + c] * (1.f / 4096.f) - mean * mean;
  var = fmaxf(var, 0.f);
  const float v = (x[i] - mean) * rsqrtf(var + 1e-5f) * gamma[c] + beta[c];
  x[i] = fmaxf(v, 0.f);
}

// ---------------------------------------------------------------------------
extern "C" void kernel_launch(void* const* d_in, const int* in_sizes, int n_in,
                              void* d_out, int out_size, void* d_ws, size_t ws_size,
                              hipStream_t stream) {
  const float* probs   = (const float*)d_in[0];
  const float* bbox    = (const float*)d_in[1];
  const float* query   = (const float*)d_in[2];
  const float* node    = (const float*)d_in[3];
  const float* mlp_w1  = (const float*)d_in[4];
  const float* mlp_b1  = (const float*)d_in[5];
  const float* mlp_w2  = (const float*)d_in[6];
  const float* mlp_b2  = (const float*)d_in[7];
  const float* conv_w1 = (const float*)d_in[8];
  const float* conv_b1 = (const float*)d_in[9];
  const float* conv_w2 = (const float*)d_in[10];
  const float* conv_b2 = (const float*)d_in[11];
  const float* gamma   = (const float*)d_in[12];
  const float* beta    = (const float*)d_in[13];

  // --- workspace layout (peak 28,577,792 floats = 114.3 MB) ---
  float* ws = (float*)d_ws;
  size_t off = 0;
  float* adj  = ws + off;  off += (size_t)N_NODES * N_NODES;     // 16,777,216 f
  u16* w1t_hi = (u16*)(ws + off);                                // [1024][5120] u16 x2
  u16* w1t_lo = w1t_hi + (size_t)HMLP * K1PAD;
  off += (size_t)HMLP * K1PAD;                                   // 5,242,880 f (both planes)
  u16* h_hi = (u16*)(ws + off);                                  // [4096][1024] u16 x2
  u16* h_lo = h_hi + (size_t)N_NODES * HMLP;
  off += (size_t)N_NODES * HMLP;                                 // 4,194,304 f (both planes)
  u16* w1ct_hi = (u16*)(ws + off);                               // [256][4096] u16 x2
  u16* w1ct_lo = w1ct_hi + (size_t)256 * D_DIM;
  const size_t w1ct_off = off;
  off += (size_t)256 * D_DIM;                                    // 1,048,576 f (both planes) -- FIXED
  float* vals = ws + off;  off += (size_t)N_NODES * TOPK;
  int*   idxo = (int*)(ws + off); off += (size_t)N_NODES * TOPK;
  float* dinv = ws + off;  off += N_NODES;
  float* Z1   = ws + off;  off += (size_t)N_NODES * 256;         // live steps 5-7
  // --- overlays (temporally disjoint) ---
  // W2t overlays W1t region (W1t dead after gemm1)
  u16* w2t_hi = w1t_hi;
  u16* w2t_lo = w2t_hi + (size_t)N_NODES * HMLP;
  // out1 overlays w1ct region (w1ct dead after fused2; out1 written step 7)
  float* out1 = ws + w1ct_off;                                   // 1,048,576 f exactly
  // Z2/partial/colstats overlay adj (adj dead after topk)
  float* Z2       = adj;                                         // written step 9
  float* partial  = adj + (size_t)N_NODES * 256;                 // step 8
  float* colstats = partial + 128 * 512;                         // step 8

  // 1) W1t hi/lo = split-transpose(mlp_w1)        [1024][5120]
  transpose_split<<<dim3(K1PAD / 64, HMLP / 64), 256, 0, stream>>>(
      mlp_w1, KCAT, HMLP, K1PAD, w1t_hi, w1t_lo);
  // 2) W1Ct hi/lo = split-transpose(conv_w1)      [256][4096]
  transpose_split<<<dim3(D_DIM / 64, 256 / 64), 256, 0, stream>>>(
      conv_w1, D_DIM, 256, D_DIM, w1ct_hi, w1ct_lo);
  // 3) h = relu(concat @ W1 + b1) -> bf16 hi/lo   (4096 x 1024)
  gemm1_kernel<<<dim3(HMLP / 64, N_NODES / 128), 256, 0, stream>>>(
      query, probs, bbox, w1t_hi, w1t_lo, mlp_b1, h_hi, h_lo);
  // 4) W2t hi/lo = split-transpose(mlp_w2)        [4096][1024]
  transpose_split<<<dim3(HMLP / 64, N_NODES / 64), 256, 0, stream>>>(
      mlp_w2, HMLP, N_NODES, HMLP, w2t_hi, w2t_lo);
  // 5) fused: Z1 = node @ conv_w1 (128 blocks) + adj = h @ W2 + b2 (2048)
  fused2_kernel<<<128 + (N_NODES / 64) * (N_NODES / 128), 256, 0, stream>>>(
      h_hi, h_lo, w2t_hi, w2t_lo, mlp_b2, adj, node, w1ct_hi, w1ct_lo, Z1);
  // 6) top-32 per row + dinv
  topk_kernel<<<N_NODES, 256, 0, stream>>>(adj, vals, idxo, dinv);
  // 7) out1 = gather-agg(Z1) + conv_b1   (wn inlined)
  agg_kernel<<<N_NODES, 256, 0, stream>>>(Z1, vals, idxo, dinv, conv_b1, out1);
  // 8) BatchNorm (batch stats) + relu, in place
  bn_partial<<<128, 256, 0, stream>>>(out1, partial);
  bn_reduce<<<512, 256, 0, stream>>>(partial, colstats);
  bn_apply<<<N_NODES, 256, 0, stream>>>(out1, colstats, gamma, beta);
  // 9) Z2 = y @ conv_w2 (fp32)                    (4096 x 256)
  gemm_small<<<dim3(256 / 64, N_NODES / 64), 256, 0, stream>>>(
      out1, conv_w2, Z2, N_NODES, 256, 256);
  // 10) out = gather-agg(Z2) + conv_b2
  agg_kernel<<<N_NODES, 256, 0, stream>>>(Z2, vals, idxo, dinv, conv_b2, (float*)d_out);
}